// Round 1
// baseline (180.737 us; speedup 1.0000x reference)
//
#include <hip/hip_runtime.h>
#include <hip/hip_bf16.h>

// Problem constants (from setup_inputs): B=2, H=64, W=192, num=4
constexpr int W = 192;
constexpr int H = 64;
constexpr int N = H * W;      // 12288
constexpr int B = 2;
constexpr int NUM = 4;
constexpr float THRESH = 0.001f;
constexpr int CH = 1024;      // LDS candidate chunk

// ws layout (ints): [0..1] = per-batch valid count; [16 + b*N ...] = valid index list
__global__ void compact_kernel(const float* __restrict__ S, int* __restrict__ ws) {
    const int b = blockIdx.x;
    __shared__ int sh_cnt;
    if (threadIdx.x == 0) sh_cnt = 0;
    __syncthreads();
    const float* Sb = S + b * N;
    int* lb = ws + 16 + b * N;
    for (int i = threadIdx.x; i < N; i += blockDim.x) {
        if (Sb[i] > THRESH) {
            int p = atomicAdd(&sh_cnt, 1);
            lb[p] = i;   // order irrelevant: selection is lexicographic in (d, idx)
        }
    }
    __syncthreads();
    if (threadIdx.x == 0) ws[b] = sh_cnt;
}

__global__ __launch_bounds__(256) void knn_kernel(const int* __restrict__ ws,
                                                  float* __restrict__ out) {
    const int b = blockIdx.y;
    const int n = blockIdx.x * 256 + threadIdx.x;
    const int yni = n / W;
    const int xni = n - yni * W;
    const float xn = (float)xni;
    const float yn = (float)yni;
    const int V = ws[b];
    const int* lb = ws + 16 + b * N;

    __shared__ float shx[CH];
    __shared__ float shy[CH];
    __shared__ int   shm[CH];

    // top-4 (d, m) ascending lexicographic; all arithmetic exact (ints < 2^24)
    float d0 = INFINITY, d1 = INFINITY, d2 = INFINITY, d3 = INFINITY;
    int   m0 = 0x7FFFFFFF, m1 = 0x7FFFFFFF, m2 = 0x7FFFFFFF, m3 = 0x7FFFFFFF;

    for (int base = 0; base < V; base += CH) {
        const int c = min(CH, V - base);
        __syncthreads();
        for (int i = threadIdx.x; i < c; i += 256) {
            const int m = lb[base + i];
            const int ym = m / W;          // compiler magic-mul, once per block per cand
            const int xm = m - ym * W;
            shx[i] = (float)xm;
            shy[i] = (float)ym;
            shm[i] = m;
        }
        __syncthreads();
        for (int i = 0; i < c; ++i) {
            const float dx = xn - shx[i];  // same-addr LDS read -> broadcast, no conflict
            const float dy = yn - shy[i];
            const float d = dx * dx + dy * dy;
            const int m = shm[i];
            if ((d < d3) || (d == d3 && m < m3)) {
                if (!((d < d2) || (d == d2 && m < m2))) { d3 = d; m3 = m; }
                else {
                    d3 = d2; m3 = m2;
                    if (!((d < d1) || (d == d1 && m < m1))) { d2 = d; m2 = m; }
                    else {
                        d2 = d1; m2 = m1;
                        if (!((d < d0) || (d == d0 && m < m0))) { d1 = d; m1 = m; }
                        else { d1 = d0; m1 = m0; d0 = d; m0 = m; }
                    }
                }
            }
        }
    }

    const int ms[NUM] = {m0, m1, m2, m3};
    float* argout = out + (size_t)B * 2 * NUM * N;  // args region, written as float values
#pragma unroll
    for (int k = 0; k < NUM; ++k) {
        const int m = ms[k];
        const int ym = m / W;
        const int xm = m - ym * W;
        // IPCnum[b, 0, k, n] = x_m - x_n ; IPCnum[b, 1, k, n] = y_m - y_n
        out[(((b * 2 + 0) * NUM + k) * N) + n] = (float)xm - xn;
        out[(((b * 2 + 1) * NUM + k) * N) + n] = (float)ym - yn;
        argout[(b * NUM + k) * N + n] = (float)m;
    }
}

extern "C" void kernel_launch(void* const* d_in, const int* in_sizes, int n_in,
                              void* d_out, int out_size, void* d_ws, size_t ws_size,
                              hipStream_t stream) {
    const float* S = (const float*)d_in[0];   // [B,1,H,W] float32
    float* out = (float*)d_out;               // IPCnum floats then args-as-floats
    int* ws = (int*)d_ws;

    compact_kernel<<<dim3(B), dim3(256), 0, stream>>>(S, ws);
    knn_kernel<<<dim3(N / 256, B), dim3(256), 0, stream>>>(ws, out);
}

// Round 2
// 78.140 us; speedup vs baseline: 2.3130x; 2.3130x over previous
//
#include <hip/hip_runtime.h>
#include <hip/hip_bf16.h>
#include <limits.h>

// Problem constants (from setup_inputs): B=2, H=64, W=192, num=4
constexpr int W = 192;
constexpr int H = 64;
constexpr int N = H * W;      // 12288
constexpr int B = 2;
constexpr int NUM = 4;
constexpr float THRESH = 0.001f;
constexpr int SLICES = 8;     // one wave per slice
constexpr int QPB = 64;       // queries per block (one lane per query)
constexpr int THREADS = SLICES * QPB;  // 512
constexpr int CH = 1024;      // LDS candidate chunk (ints)
constexpr int PAD = 0x3FFFFFFF; // decodes x=255,y=255,m=16383 -> d>=40960 > max real 40450

// ws layout (ints): [0..B-1] per-batch valid count (memset to 0 before launch);
//                   [16 + b*N ...] packed candidates: x | y<<8 | idx<<16
__global__ void compact_kernel(const float* __restrict__ S, int* __restrict__ ws) {
    const int b = blockIdx.y;
    const int i0 = (blockIdx.x * 256 + threadIdx.x) * 4;
    const float4 v = *(const float4*)(S + b * N + i0);
    int* lb = ws + 16 + b * N;
    const int lane = threadIdx.x & 63;
#pragma unroll
    for (int j = 0; j < 4; ++j) {
        const int i = i0 + j;
        const float val = (j == 0) ? v.x : (j == 1) ? v.y : (j == 2) ? v.z : v.w;
        const bool valid = val > THRESH;
        const unsigned long long mask = __ballot(valid);
        const int cnt = __popcll(mask);
        int base = 0;
        if (lane == 0 && cnt) base = atomicAdd(&ws[b], cnt);
        base = __shfl(base, 0);
        if (valid) {
            const int pos = base + __popcll(mask & ((1ull << lane) - 1ull));
            const int ym = i / W;
            const int xm = i - ym * W;
            lb[pos] = xm | (ym << 8) | (i << 16);
        }
    }
}

// branchless insert of key into sorted (K0<=K1<=K2<=K3)
#define INSERT(key, K0, K1, K2, K3) do {            \
    int _t = max((key), K0); K0 = min((key), K0);   \
    int _u = max(_t, K1);    K1 = min(_t, K1);      \
    int _v = max(_u, K2);    K2 = min(_u, K2);      \
    K3 = min(_v, K3);                               \
} while (0)

// decode packed candidate p, build key = (d<<14)|m, insert
#define PROC(p, K0, K1, K2, K3) do {                \
    const int _xm = (p) & 255;                      \
    const int _ym = ((p) >> 8) & 255;               \
    const int _dx = _xm - xn;                       \
    const int _dy = _ym - yn;                       \
    const int _d = __mul24(_dx, _dx) + __mul24(_dy, _dy); \
    const int _key = (_d << 14) | ((p) >> 16);      \
    INSERT(_key, K0, K1, K2, K3);                   \
} while (0)

__global__ __launch_bounds__(THREADS) void knn_kernel(const int* __restrict__ ws,
                                                      float* __restrict__ out) {
    const int b = blockIdx.y;
    const int q = threadIdx.x & (QPB - 1);   // lane = query within block
    const int s = threadIdx.x >> 6;          // wave = candidate slice
    const int n = blockIdx.x * QPB + q;
    const int yn = n / W;
    const int xn = n - yn * W;
    const int V = ws[b];
    const int* lb = ws + 16 + b * N;

    __shared__ int cand[CH];
    __shared__ int keym[NUM][THREADS];

    // two interleaved sorted-4 ladders for ILP
    int k0 = INT_MAX, k1 = INT_MAX, k2 = INT_MAX, k3 = INT_MAX;
    int a0 = INT_MAX, a1 = INT_MAX, a2 = INT_MAX, a3 = INT_MAX;

    for (int base = 0; base < V; base += CH) {
        const int c = min(CH, V - base);
        const int cpad = (c + 2 * SLICES - 1) & ~(2 * SLICES - 1);
        __syncthreads();
        for (int i = threadIdx.x; i < c; i += THREADS) cand[i] = lb[base + i];
        for (int i = c + threadIdx.x; i < cpad; i += THREADS) cand[i] = PAD;
        __syncthreads();
        // slice s scans pairs {s*2, s*2+1} strided by 16; reads are wave-uniform (broadcast)
        for (int i = s * 2; i < cpad; i += SLICES * 2) {
            const int pA = cand[i];
            const int pB = cand[i + 1];
            PROC(pA, k0, k1, k2, k3);
            PROC(pB, a0, a1, a2, a3);
        }
    }
    // merge ladder A into K
    INSERT(a0, k0, k1, k2, k3);
    INSERT(a1, k0, k1, k2, k3);
    INSERT(a2, k0, k1, k2, k3);
    INSERT(a3, k0, k1, k2, k3);

    keym[0][threadIdx.x] = k0;
    keym[1][threadIdx.x] = k1;
    keym[2][threadIdx.x] = k2;
    keym[3][threadIdx.x] = k3;
    __syncthreads();

    if (s == 0) {
        // merge the other 7 slices' top-4 for this query
#pragma unroll
        for (int sl = 1; sl < SLICES; ++sl) {
#pragma unroll
            for (int k = 0; k < NUM; ++k) {
                const int key = keym[k][sl * QPB + q];
                INSERT(key, k0, k1, k2, k3);
            }
        }
        const int keys[NUM] = {k0, k1, k2, k3};
        float* argout = out + (size_t)B * 2 * NUM * N;
#pragma unroll
        for (int k = 0; k < NUM; ++k) {
            const int m = keys[k] & 16383;
            const int ym = m / W;
            const int xm = m - ym * W;
            out[(((b * 2 + 0) * NUM + k) * N) + n] = (float)(xm - xn);
            out[(((b * 2 + 1) * NUM + k) * N) + n] = (float)(ym - yn);
            argout[(b * NUM + k) * N + n] = (float)m;
        }
    }
}

extern "C" void kernel_launch(void* const* d_in, const int* in_sizes, int n_in,
                              void* d_out, int out_size, void* d_ws, size_t ws_size,
                              hipStream_t stream) {
    const float* S = (const float*)d_in[0];   // [B,1,H,W] float32
    float* out = (float*)d_out;               // IPCnum floats then args-as-floats
    int* ws = (int*)d_ws;

    hipMemsetAsync(ws, 0, 64, stream);        // zero the per-batch counters
    compact_kernel<<<dim3(N / 1024, B), dim3(256), 0, stream>>>(S, ws);
    knn_kernel<<<dim3(N / QPB, B), dim3(THREADS), 0, stream>>>(ws, out);
}

// Round 3
// 73.882 us; speedup vs baseline: 2.4463x; 1.0576x over previous
//
#include <hip/hip_runtime.h>
#include <hip/hip_bf16.h>
#include <limits.h>

// Problem constants (from setup_inputs): B=2, H=64, W=192, num=4
constexpr int W = 192;
constexpr int H = 64;
constexpr int N = H * W;      // 12288
constexpr int B = 2;
constexpr int NUM = 4;
constexpr float THRESH = 0.001f;
constexpr int SLICES = 8;     // one wave per candidate slice
constexpr int QPB = 64;       // queries per block (one lane per query)
constexpr int THREADS = SLICES * QPB;  // 512
constexpr int PAD = 0x3FFFFFFF; // decodes x=255,y=255,m=16383 -> d>=40960 > max real 40450

// branchless insert of key into sorted (K0<=K1<=K2<=K3)
#define INSERT(key, K0, K1, K2, K3) do {            \
    int _t = max((key), K0); K0 = min((key), K0);   \
    int _u = max(_t, K1);    K1 = min(_t, K1);      \
    int _v = max(_u, K2);    K2 = min(_u, K2);      \
    K3 = min(_v, K3);                               \
} while (0)

// decode packed candidate p, build key = (d<<14)|m, insert
// all integer arithmetic exact; key order == lexicographic (d, m) order
#define PROC(p, K0, K1, K2, K3) do {                \
    const int _xm = (p) & 255;                      \
    const int _ym = ((p) >> 8) & 255;               \
    const int _dx = _xm - xn;                       \
    const int _dy = _ym - yn;                       \
    const int _d = __mul24(_dx, _dx) + __mul24(_dy, _dy); \
    const int _key = (_d << 14) | ((p) >> 16);      \
    INSERT(_key, K0, K1, K2, K3);                   \
} while (0)

__global__ __launch_bounds__(THREADS) void dist_kernel(const float* __restrict__ S,
                                                       float* __restrict__ out) {
    const int b = blockIdx.y;
    const int q = threadIdx.x & (QPB - 1);   // lane = query within block
    const int s = threadIdx.x >> 6;          // wave = candidate slice
    const int n = blockIdx.x * QPB + q;
    const int yn = n / W;
    const int xn = n - yn * W;
    const int lane = threadIdx.x & 63;

    __shared__ int cand[N];                  // worst-case all-valid: 48 KB
    __shared__ int keym[NUM][THREADS];       // 8 KB cross-wave merge buffer
    __shared__ int sh_cnt;

    if (threadIdx.x == 0) sh_cnt = 0;
    __syncthreads();

    // ---- Phase 1: block-local compaction of batch b's sparse map into LDS ----
    const float* Sb = S + b * N;
#pragma unroll
    for (int k = 0; k < N / (THREADS * 4); ++k) {      // 6 iterations
        const int i0 = (k * THREADS + threadIdx.x) * 4;
        const float4 v = *(const float4*)(Sb + i0);    // coalesced, L2-resident
#pragma unroll
        for (int j = 0; j < 4; ++j) {
            const int i = i0 + j;
            const float val = (j == 0) ? v.x : (j == 1) ? v.y : (j == 2) ? v.z : v.w;
            const bool valid = val > THRESH;
            const unsigned long long mask = __ballot(valid);
            const int cnt = __popcll(mask);
            int base = 0;
            if (lane == 0 && cnt) base = atomicAdd(&sh_cnt, cnt);
            base = __shfl(base, 0);
            if (valid) {   // order irrelevant: selection is lexicographic in (d, m)
                const int pos = base + __popcll(mask & ((1ull << lane) - 1ull));
                const int ym = i / W;
                const int xm = i - ym * W;
                cand[pos] = xm | (ym << 8) | (i << 16);
            }
        }
    }
    __syncthreads();
    const int V = sh_cnt;
    const int Vpad = (V + 2 * SLICES - 1) & ~(2 * SLICES - 1);
    for (int i = V + threadIdx.x; i < Vpad; i += THREADS) cand[i] = PAD;
    __syncthreads();

    // ---- Phase 2: each slice-wave scans its candidate stripe ----
    int k0 = INT_MAX, k1 = INT_MAX, k2 = INT_MAX, k3 = INT_MAX;  // ladder A
    int a0 = INT_MAX, a1 = INT_MAX, a2 = INT_MAX, a3 = INT_MAX;  // ladder B (ILP)
    for (int i = s * 2; i < Vpad; i += SLICES * 2) {   // wave-uniform addr -> broadcast
        const int pA = cand[i];
        const int pB = cand[i + 1];
        PROC(pA, k0, k1, k2, k3);
        PROC(pB, a0, a1, a2, a3);
    }
    INSERT(a0, k0, k1, k2, k3);
    INSERT(a1, k0, k1, k2, k3);
    INSERT(a2, k0, k1, k2, k3);
    INSERT(a3, k0, k1, k2, k3);

    keym[0][threadIdx.x] = k0;
    keym[1][threadIdx.x] = k1;
    keym[2][threadIdx.x] = k2;
    keym[3][threadIdx.x] = k3;
    __syncthreads();

    // ---- Phase 3: wave 0 merges the other 7 slices, writes output ----
    if (s == 0) {
#pragma unroll
        for (int sl = 1; sl < SLICES; ++sl) {
#pragma unroll
            for (int k = 0; k < NUM; ++k) {
                const int key = keym[k][sl * QPB + q];
                INSERT(key, k0, k1, k2, k3);
            }
        }
        const int keys[NUM] = {k0, k1, k2, k3};
        float* argout = out + (size_t)B * 2 * NUM * N;  // args region, as float values
#pragma unroll
        for (int k = 0; k < NUM; ++k) {
            const int m = keys[k] & 16383;
            const int ym = m / W;
            const int xm = m - ym * W;
            // IPCnum[b, 0, k, n] = x_m - x_n ; IPCnum[b, 1, k, n] = y_m - y_n
            out[(((b * 2 + 0) * NUM + k) * N) + n] = (float)(xm - xn);
            out[(((b * 2 + 1) * NUM + k) * N) + n] = (float)(ym - yn);
            argout[(b * NUM + k) * N + n] = (float)m;
        }
    }
}

extern "C" void kernel_launch(void* const* d_in, const int* in_sizes, int n_in,
                              void* d_out, int out_size, void* d_ws, size_t ws_size,
                              hipStream_t stream) {
    const float* S = (const float*)d_in[0];   // [B,1,H,W] float32
    float* out = (float*)d_out;               // IPCnum floats then args-as-floats
    dist_kernel<<<dim3(N / QPB, B), dim3(THREADS), 0, stream>>>(S, out);
}